// Round 7
// baseline (1018.284 us; speedup 1.0000x reference)
//
#include <hip/hip_runtime.h>

// GCN 2-layer: N=200000, E=12800000, features 2 -> 16 -> 2.
// R2: rank trick -- aggregate only 2-dim vectors (before W1 / after W2).
// R4/R5: counting-sort by dst bucket (256 nodes), LDS aggregation, coalesced
//        scatter. R6: split buckets + ILP -> agg stuck at 143us: divergent 8B
//        gathers from the 1.6MB table thrash the 32KB L1; per-CU miss-tracking
//        x L2 latency caps lane-miss throughput (~90/us/CU) regardless of
//        occupancy/ILP.
// R7: 2D sort. Each dst-GROUP (1024 nodes = 4 pass-1 buckets) has its edges
//     sub-sorted by src-TILE (8192 nodes) in-place (block-exclusive sub-chunk
//     permutation, deg fused). agg stages each 64KB src-tile in LDS and
//     gathers via ds_read -- zero L1 misses on the gather path.

constexpr int N_NODES = 200000;
constexpr int N_EDGES = 12800000;
constexpr int RANGE_SHIFT = 8;                       // 256 nodes / pass-1 bucket
constexpr int K_BUCKETS = (N_NODES + 255) / 256;     // 782
constexpr int SORT_BLOCKS = 2048;
constexpr int CHUNK = N_EDGES / SORT_BLOCKS;         // 6250
constexpr int SCAN_R = SORT_BLOCKS / 256;            // 8
constexpr int N_GROUPS = 196;                        // 1024-node dst groups
constexpr int SUB = 11;                              // sub-chunks per group
constexpr int NT = 25;                               // src tiles
constexpr int TILE = 8192;                           // nodes per src tile
constexpr int GPARTS = 3;                            // agg blocks per group

// ---------------- pass-1 sort (R5-proven) ----------------

__global__ __launch_bounds__(256) void hist_kernel(const int* __restrict__ dst,
                                                   unsigned* __restrict__ blockHist) {
    __shared__ unsigned h[K_BUCKETS];
    for (int i = threadIdx.x; i < K_BUCKETS; i += 256) h[i] = 0;
    __syncthreads();
    int base = blockIdx.x * CHUNK;
    for (int e = base + threadIdx.x; e < base + CHUNK; e += 256)
        atomicAdd(&h[((unsigned)dst[e]) >> RANGE_SHIFT], 1u);
    __syncthreads();
    unsigned* row = blockHist + (size_t)blockIdx.x * K_BUCKETS;
    for (int i = threadIdx.x; i < K_BUCKETS; i += 256) row[i] = h[i];
}

__global__ __launch_bounds__(256) void scan_perblock_kernel(unsigned* __restrict__ blockHist,
                                                            unsigned* __restrict__ bucketTotal) {
    int b = blockIdx.x, t = threadIdx.x;
    unsigned v[SCAN_R], run = 0;
#pragma unroll
    for (int j = 0; j < SCAN_R; j++) v[j] = blockHist[(size_t)(SCAN_R * t + j) * K_BUCKETS + b];
#pragma unroll
    for (int j = 0; j < SCAN_R; j++) { unsigned tmp = v[j]; v[j] = run; run += tmp; }
    __shared__ unsigned sh[256];
    sh[t] = run;
    __syncthreads();
    for (int off = 1; off < 256; off <<= 1) {
        unsigned add = (t >= off) ? sh[t - off] : 0u;
        __syncthreads();
        sh[t] += add;
        __syncthreads();
    }
    unsigned excl = sh[t] - run;
#pragma unroll
    for (int j = 0; j < SCAN_R; j++)
        blockHist[(size_t)(SCAN_R * t + j) * K_BUCKETS + b] = excl + v[j];
    if (t == 255) bucketTotal[b] = sh[255];
}

__global__ __launch_bounds__(1024) void scan_buckets_kernel(const unsigned* __restrict__ bucketTotal,
                                                            unsigned* __restrict__ bucketStart) {
    __shared__ unsigned sh[1024];
    int t = threadIdx.x;
    unsigned v = (t < K_BUCKETS) ? bucketTotal[t] : 0u;
    sh[t] = v;
    __syncthreads();
    for (int off = 1; off < 1024; off <<= 1) {
        unsigned add = (t >= off) ? sh[t - off] : 0u;
        __syncthreads();
        sh[t] += add;
        __syncthreads();
    }
    if (t < K_BUCKETS) bucketStart[t] = sh[t] - v;
    if (t == K_BUCKETS - 1) bucketStart[K_BUCKETS] = sh[t];
}

// Entry packs: src (18b) | (dst & 1023) << 18   (28 bits)
__global__ __launch_bounds__(256) void scatter_kernel(const int* __restrict__ src,
                                                      const int* __restrict__ dst,
                                                      const unsigned* __restrict__ blockHist,
                                                      const unsigned* __restrict__ bucketStart,
                                                      unsigned* __restrict__ sorted) {
    __shared__ unsigned s_hist[K_BUCKETS];
    __shared__ unsigned s_cur[K_BUCKETS];
    __shared__ int      s_base[K_BUCKETS];
    __shared__ unsigned ssum[256];
    __shared__ unsigned ent[CHUNK];
    __shared__ unsigned short bk[CHUNK];

    int t = threadIdx.x;
    int base = blockIdx.x * CHUNK;
    for (int i = t; i < K_BUCKETS; i += 256) s_hist[i] = 0;
    __syncthreads();

    for (int e = base + t; e < base + CHUNK; e += 256)
        atomicAdd(&s_hist[((unsigned)dst[e]) >> RANGE_SHIFT], 1u);
    __syncthreads();

    unsigned v[4], run = 0;
#pragma unroll
    for (int j = 0; j < 4; j++) {
        int idx = 4 * t + j;
        v[j] = (idx < K_BUCKETS) ? s_hist[idx] : 0u;
    }
#pragma unroll
    for (int j = 0; j < 4; j++) { unsigned tmp = v[j]; v[j] = run; run += tmp; }
    ssum[t] = run;
    __syncthreads();
    for (int off = 1; off < 256; off <<= 1) {
        unsigned add = (t >= off) ? ssum[t - off] : 0u;
        __syncthreads();
        ssum[t] += add;
        __syncthreads();
    }
    unsigned excl = ssum[t] - run;
    const unsigned* row = blockHist + (size_t)blockIdx.x * K_BUCKETS;
#pragma unroll
    for (int j = 0; j < 4; j++) {
        int idx = 4 * t + j;
        if (idx < K_BUCKETS) {
            unsigned st = excl + v[j];
            s_cur[idx] = st;
            s_base[idx] = (int)(bucketStart[idx] + row[idx]) - (int)st;
        }
    }
    __syncthreads();

    for (int e = base + t; e < base + CHUNK; e += 256) {
        unsigned d = (unsigned)dst[e];
        unsigned s = (unsigned)src[e];
        unsigned b = d >> RANGE_SHIFT;
        unsigned lpos = atomicAdd(&s_cur[b], 1u);
        ent[lpos] = s | ((d & 1023u) << 18);     // 10-bit local dst (group-relative)
        bk[lpos] = (unsigned short)b;
    }
    __syncthreads();

    for (int i = t; i < CHUNK; i += 256) {
        unsigned b = bk[i];
        sorted[s_base[b] + i] = ent[i];
    }
}

// ---------------- pass-2: in-place sub-sort by src-tile, deg fused ----------
// Grid: N_GROUPS * SUB. Block owns sub-chunk [c0,c1) of its group's run:
// reads it fully into LDS, permutes by src-tile, writes back to [c0,c1).
__global__ __launch_bounds__(256) void scatter2_kernel(unsigned* __restrict__ sorted,
                                                       const unsigned* __restrict__ bucketStart,
                                                       unsigned short* __restrict__ lstart,
                                                       unsigned short* __restrict__ pcnt) {
    __shared__ unsigned ent[6144];
    __shared__ unsigned char bk[6144];
    __shared__ unsigned cnt[1024];
    __shared__ unsigned h[NT], cur[NT];
    int t = threadIdx.x;
    int g = blockIdx.x / SUB, s = blockIdx.x % SUB;
    int gS = bucketStart[4 * g];
    int gE = bucketStart[min(4 * g + 4, K_BUCKETS)];
    int len = gE - gS;
    int c0 = gS + (int)((long long)len * s / SUB);
    int c1 = gS + (int)((long long)len * (s + 1) / SUB);
    int n = c1 - c0;
    for (int i = t; i < 1024; i += 256) cnt[i] = 0;
    if (t < NT) h[t] = 0;
    __syncthreads();
    for (int i = t; i < n; i += 256) {
        unsigned w = sorted[c0 + i];
        ent[i] = w;
        unsigned tile = (w & 0x3FFFFu) >> 13;
        bk[i] = (unsigned char)tile;
        atomicAdd(&h[tile], 1u);
        atomicAdd(&cnt[w >> 18], 1u);       // degree (local dst)
    }
    __syncthreads();
    if (t == 0) {                            // exclusive scan over 25 bins
        unsigned r = 0;
        for (int j = 0; j < NT; j++) { unsigned c = h[j]; h[j] = r; cur[j] = r; r += c; }
    }
    __syncthreads();
    unsigned b26 = (unsigned)blockIdx.x * 26u;
    if (t < NT) lstart[b26 + t] = (unsigned short)h[t];
    if (t == 0) lstart[b26 + NT] = (unsigned short)n;
    for (int i = t; i < n; i += 256) {
        unsigned r = atomicAdd(&cur[bk[i]], 1u);
        sorted[c0 + r] = ent[i];             // block-exclusive range: race-free
    }
    for (int i = t; i < 1024; i += 256)
        pcnt[(size_t)blockIdx.x * 1024 + i] = (unsigned short)cnt[i];
}

// ---------------- GCN phase ----------------

__global__ __launch_bounds__(256) void node1_kernel(const float2* __restrict__ x,
                                                    const unsigned short* __restrict__ pcnt,
                                                    float* __restrict__ dinv,
                                                    float2* __restrict__ u) {
    int i = blockIdx.x * 256 + threadIdx.x;
    if (i >= N_NODES) return;
    int g = i >> 10, l = i & 1023;
    unsigned c = 1;  // +1 self loop
#pragma unroll
    for (int s = 0; s < SUB; s++) c += pcnt[(size_t)(g * SUB + s) * 1024 + l];
    float di = rsqrtf((float)c);
    dinv[i] = di;
    float2 xi = x[i];
    u[i] = make_float2(di * xi.x, di * xi.y);
}

// One block per (group, part): part owns tiles {p, p+3, ...}. Stage tile in
// LDS, gather from LDS, accumulate into LDS acc[1024], write float2 partial.
__global__ __launch_bounds__(256) void agg_tile_kernel(const unsigned* __restrict__ sorted,
                                                       const unsigned* __restrict__ bucketStart,
                                                       const unsigned short* __restrict__ lstart,
                                                       const float2* __restrict__ table,
                                                       float2* __restrict__ part) {
    __shared__ float2 tileBuf[TILE];
    __shared__ float accX[1024], accY[1024];
    __shared__ int runS[SUB], runP[SUB + 1];
    int t = threadIdx.x;
    int g = blockIdx.x / GPARTS, p = blockIdx.x % GPARTS;
    int gS = bucketStart[4 * g];
    int gE = bucketStart[min(4 * g + 4, K_BUCKETS)];
    int len = gE - gS;
    for (int i = t; i < 1024; i += 256) { accX[i] = 0.f; accY[i] = 0.f; }
    for (int tile = p; tile < NT; tile += GPARTS) {
        __syncthreads();   // prior iteration done with tileBuf/runP; acc init visible
        int base = tile * TILE;
        int nf4 = min(TILE, N_NODES - base) >> 1;          // float4 count
        const float4* src4 = (const float4*)(table + base);
        float4* dst4 = (float4*)tileBuf;
        for (int j = t; j < nf4; j += 256) dst4[j] = src4[j];
        if (t < SUB) {
            int c0 = gS + (int)((long long)len * t / SUB);
            unsigned b26 = (unsigned)(g * SUB + t) * 26u;
            int st = lstart[b26 + tile];
            int en = lstart[b26 + tile + 1];
            runS[t] = c0 + st;
            runP[t] = en - st;                              // length (temp)
        }
        __syncthreads();
        if (t == 0) {
            int r = 0;
            for (int s2 = 0; s2 < SUB; s2++) { int L = runP[s2]; runP[s2] = r; r += L; }
            runP[SUB] = r;
        }
        __syncthreads();
        int total = runP[SUB];
        for (int k = t; k < total; k += 256) {
            int s2 = 0;
            while (runP[s2 + 1] <= k) s2++;
            unsigned w = sorted[runS[s2] + (k - runP[s2])];
            float2 v = tileBuf[w & 8191u];
            unsigned l = w >> 18;
            atomicAdd(&accX[l], v.x);
            atomicAdd(&accY[l], v.y);
        }
    }
    __syncthreads();
    for (int i = t; i < 1024; i += 256)
        part[(size_t)blockIdx.x * 1024 + i] = make_float2(accX[i], accY[i]);
}

__global__ __launch_bounds__(256) void node2_kernel(const float2* __restrict__ u,
                                                    const float2* __restrict__ part,
                                                    const float* __restrict__ W1,
                                                    const float* __restrict__ b1,
                                                    const float* __restrict__ W2,
                                                    const float* __restrict__ dinv,
                                                    float2* __restrict__ g2) {
    int i = blockIdx.x * 256 + threadIdx.x;
    if (i >= N_NODES) return;
    int g = i >> 10, l = i & 1023;
    float ax = 0.f, ay = 0.f;
#pragma unroll
    for (int p = 0; p < GPARTS; p++) {
        float2 v = part[(size_t)(g * GPARTS + p) * 1024 + l];
        ax += v.x; ay += v.y;
    }
    float di = dinv[i];
    float2 uu = u[i];
    float c0 = di * (ax + uu.x);
    float c1 = di * (ay + uu.y);
    float a0 = 0.f, a1 = 0.f;
#pragma unroll
    for (int f = 0; f < 16; f++) {
        float o = fmaxf(c0 * W1[f] + c1 * W1[16 + f] + b1[f], 0.f);  // W1 (2,16)
        a0 += o * W2[2 * f];                                         // W2 (16,2)
        a1 += o * W2[2 * f + 1];
    }
    g2[i] = make_float2(di * a0, di * a1);
}

__global__ __launch_bounds__(256) void node3_kernel(const float2* __restrict__ g2,
                                                    const float2* __restrict__ part,
                                                    const float* __restrict__ b2,
                                                    const float* __restrict__ dinv,
                                                    float2* __restrict__ out) {
    int i = blockIdx.x * 256 + threadIdx.x;
    if (i >= N_NODES) return;
    int g = i >> 10, l = i & 1023;
    float ax = 0.f, ay = 0.f;
#pragma unroll
    for (int p = 0; p < GPARTS; p++) {
        float2 v = part[(size_t)(g * GPARTS + p) * 1024 + l];
        ax += v.x; ay += v.y;
    }
    float di = dinv[i];
    float2 gg = g2[i];
    out[i] = make_float2(di * (ax + gg.x) + b2[0],
                         di * (ay + gg.y) + b2[1]);
}

// ---------------- fallback path (R2-style, 8 MB ws) ----------------

__global__ __launch_bounds__(256) void fb_deg(const int* __restrict__ dst, int* __restrict__ degi) {
    int e = blockIdx.x * 256 + threadIdx.x;
    if (e < N_EDGES) atomicAdd(&degi[dst[e]], 1);
}
__global__ __launch_bounds__(256) void fb_node1(const float* __restrict__ x, const int* __restrict__ degi,
                                                float* __restrict__ dinv, float2* __restrict__ u) {
    int i = blockIdx.x * 256 + threadIdx.x;
    if (i >= N_NODES) return;
    float di = rsqrtf((float)(degi[i] + 1));
    dinv[i] = di;
    float2 xi = ((const float2*)x)[i];
    u[i] = make_float2(di * xi.x, di * xi.y);
}
__global__ __launch_bounds__(256) void fb_agg(const int* __restrict__ src, const int* __restrict__ dst,
                                              const float2* __restrict__ table, float* __restrict__ acc) {
    int e = blockIdx.x * 256 + threadIdx.x;
    if (e >= N_EDGES) return;
    float2 v = table[src[e]];
    size_t d = dst[e];
    unsafeAtomicAdd(&acc[2 * d], v.x);
    unsafeAtomicAdd(&acc[2 * d + 1], v.y);
}
__global__ __launch_bounds__(256) void fb_node2(const float2* __restrict__ u, const float2* __restrict__ A1,
                                                const float* __restrict__ W1, const float* __restrict__ b1,
                                                const float* __restrict__ W2, const float* __restrict__ dinv,
                                                float2* __restrict__ g2) {
    int i = blockIdx.x * 256 + threadIdx.x;
    if (i >= N_NODES) return;
    float di = dinv[i];
    float2 a = A1[i], uu = u[i];
    float c0 = di * (a.x + uu.x), c1 = di * (a.y + uu.y);
    float a0 = 0.f, a1 = 0.f;
#pragma unroll
    for (int f = 0; f < 16; f++) {
        float o = fmaxf(c0 * W1[f] + c1 * W1[16 + f] + b1[f], 0.f);
        a0 += o * W2[2 * f];
        a1 += o * W2[2 * f + 1];
    }
    g2[i] = make_float2(di * a0, di * a1);
}
__global__ __launch_bounds__(256) void fb_node3(const float2* __restrict__ g2, const float2* __restrict__ A2,
                                                const float* __restrict__ b2, const float* __restrict__ dinv,
                                                float2* __restrict__ out) {
    int i = blockIdx.x * 256 + threadIdx.x;
    if (i >= N_NODES) return;
    float di = dinv[i];
    float2 a = A2[i], g = g2[i];
    out[i] = make_float2(di * (a.x + g.x) + b2[0], di * (a.y + g.y) + b2[1]);
}

// ---------------- launcher ----------------

extern "C" void kernel_launch(void* const* d_in, const int* in_sizes, int n_in,
                              void* d_out, int out_size, void* d_ws, size_t ws_size,
                              hipStream_t stream) {
    const float* x  = (const float*)d_in[0];
    const float* W1 = (const float*)d_in[1];
    const float* b1 = (const float*)d_in[2];
    const float* W2 = (const float*)d_in[3];
    const float* b2 = (const float*)d_in[4];
    const int* ei   = (const int*)d_in[5];   // (2,E): row 0 = src, row 1 = dst
    const int* src = ei;
    const int* dst = ei + N_EDGES;
    float2* out = (float2*)d_out;

    // ws layout (4B words):
    //   sorted  [12,800,000)
    //   region  [1,601,536)  -- time-multiplexed:
    //       blockHist u32 (hist..scatter1)          1,601,536 words
    //       lstart u16 at region[0..28,028)         (scatter2..agg2)
    //       pcnt u16 at region[28,028..1,131,900)   (scatter2..node1)
    //       part float2 at region[28,028..1,232,252) (agg1..node3)
    //   bucketTotal [784)  bucketStart [784)
    //   dinv [200,000)  u [400,000)  g2 [400,000)   (u 16B-aligned for float4)
    const size_t REGION = 1601536;
    const size_t need = ((size_t)N_EDGES + REGION + 784 + 784
                         + N_NODES + 2 * (size_t)N_NODES + 2 * (size_t)N_NODES) * 4;

    if (ws_size >= need) {
        unsigned* sorted      = (unsigned*)d_ws;
        unsigned* region      = sorted + N_EDGES;
        unsigned* blockHist   = region;
        unsigned short* lstart = (unsigned short*)region;
        unsigned short* pcnt   = (unsigned short*)(region + 28028);
        float2*   part        = (float2*)(region + 28028);
        unsigned* bucketTotal = region + REGION;
        unsigned* bucketStart = bucketTotal + 784;
        float*    dinv        = (float*)(bucketStart + 784);
        float2*   u           = (float2*)(dinv + N_NODES);
        float2*   g2          = u + N_NODES;

        hist_kernel<<<SORT_BLOCKS, 256, 0, stream>>>(dst, blockHist);
        scan_perblock_kernel<<<K_BUCKETS, 256, 0, stream>>>(blockHist, bucketTotal);
        scan_buckets_kernel<<<1, 1024, 0, stream>>>(bucketTotal, bucketStart);
        scatter_kernel<<<SORT_BLOCKS, 256, 0, stream>>>(src, dst, blockHist, bucketStart, sorted);
        scatter2_kernel<<<N_GROUPS * SUB, 256, 0, stream>>>(sorted, bucketStart, lstart, pcnt);
        node1_kernel<<<K_BUCKETS, 256, 0, stream>>>((const float2*)x, pcnt, dinv, u);
        agg_tile_kernel<<<N_GROUPS * GPARTS, 256, 0, stream>>>(sorted, bucketStart, lstart, u, part);
        node2_kernel<<<K_BUCKETS, 256, 0, stream>>>(u, part, W1, b1, W2, dinv, g2);
        agg_tile_kernel<<<N_GROUPS * GPARTS, 256, 0, stream>>>(sorted, bucketStart, lstart, g2, part);
        node3_kernel<<<K_BUCKETS, 256, 0, stream>>>(g2, part, b2, dinv, out);
    } else {
        // R2-style fallback (8 MB ws): global atomics, ~3.1 ms.
        float* ws = (float*)d_ws;
        int*   degi = (int*)ws;
        float* A1   = ws + N_NODES;
        float* A2   = A1 + 2 * (size_t)N_NODES;
        float* dinvF = A2 + 2 * (size_t)N_NODES;
        float2* uF  = (float2*)(dinvF + N_NODES);
        float2* g2F = uF + N_NODES;
        constexpr int EB = (N_EDGES + 255) / 256;
        constexpr int NB = (N_NODES + 255) / 256;
        hipMemsetAsync(degi, 0, 5 * (size_t)N_NODES * sizeof(float), stream);
        fb_deg<<<EB, 256, 0, stream>>>(dst, degi);
        fb_node1<<<NB, 256, 0, stream>>>(x, degi, dinvF, uF);
        fb_agg<<<EB, 256, 0, stream>>>(src, dst, uF, A1);
        fb_node2<<<NB, 256, 0, stream>>>(uF, (const float2*)A1, W1, b1, W2, dinvF, g2F);
        fb_agg<<<EB, 256, 0, stream>>>(src, dst, g2F, A2);
        fb_node3<<<NB, 256, 0, stream>>>(g2F, (const float2*)A2, b2, dinvF, out);
    }
}

// Round 8
// 739.463 us; speedup vs baseline: 1.3771x; 1.3771x over previous
//
#include <hip/hip_runtime.h>

// GCN 2-layer: N=200000, E=12800000, features 2 -> 16 -> 2.
// R2: rank trick -- aggregate only 2-dim vectors (before W1 / after W2).
// R4/R5: counting-sort by dst bucket + LDS aggregation, coalesced scatter.
// R6: agg = 143us, L1-miss-bound (~0.15 miss/cyc/CU tag-latency cap).
// R7 FAILED: LDS staging of src tiles -> 74KB LDS, 2 blocks/CU, redundant
//     staging, serial run search. 360us.
// R8: keep R6's lean global-gather agg; add 2D edge order (dst-group 2048 ->
//     src-tile 2048) via cheap in-place LDS sub-sort (scatter2, deg fused).
//     L1 misses drop analytically N^2/(8G): 12.8M -> 2.44M per pass. sorted
//     stream read via nontemporal loads so it doesn't evict the gather window.

constexpr int N_NODES = 200000;
constexpr int N_EDGES = 12800000;
constexpr int RANGE_SHIFT = 8;                       // 256 nodes / pass-1 bucket
constexpr int K_BUCKETS = (N_NODES + 255) / 256;     // 782
constexpr int SORT_BLOCKS = 2048;
constexpr int CHUNK = N_EDGES / SORT_BLOCKS;         // 6250
constexpr int SCAN_R = SORT_BLOCKS / 256;            // 8
constexpr int GSHIFT = 11;                           // dst-group = 2048 nodes
constexpr int G_NODES = 2048;
constexpr int N_GROUPS = 98;                         // ceil(200000/2048)
constexpr int SUB = 22;                              // sub-chunks per group
constexpr int CAP = 6400;                            // scatter2 LDS capacity
constexpr int TSHIFT = 11;                           // src tile = 2048 nodes
constexpr int NT = 98;                               // src tiles
constexpr int MAXP = 7;
constexpr int MAXRUNS = ((NT + 3) / 4) * SUB;        // 550 (for P=4 worst case)

// ---------------- pass-1 sort (R5-proven) ----------------

__global__ __launch_bounds__(256) void hist_kernel(const int* __restrict__ dst,
                                                   unsigned* __restrict__ blockHist) {
    __shared__ unsigned h[K_BUCKETS];
    for (int i = threadIdx.x; i < K_BUCKETS; i += 256) h[i] = 0;
    __syncthreads();
    int base = blockIdx.x * CHUNK;
    for (int e = base + threadIdx.x; e < base + CHUNK; e += 256)
        atomicAdd(&h[((unsigned)dst[e]) >> RANGE_SHIFT], 1u);
    __syncthreads();
    unsigned* row = blockHist + (size_t)blockIdx.x * K_BUCKETS;
    for (int i = threadIdx.x; i < K_BUCKETS; i += 256) row[i] = h[i];
}

__global__ __launch_bounds__(256) void scan_perblock_kernel(unsigned* __restrict__ blockHist,
                                                            unsigned* __restrict__ bucketTotal) {
    int b = blockIdx.x, t = threadIdx.x;
    unsigned v[SCAN_R], run = 0;
#pragma unroll
    for (int j = 0; j < SCAN_R; j++) v[j] = blockHist[(size_t)(SCAN_R * t + j) * K_BUCKETS + b];
#pragma unroll
    for (int j = 0; j < SCAN_R; j++) { unsigned tmp = v[j]; v[j] = run; run += tmp; }
    __shared__ unsigned sh[256];
    sh[t] = run;
    __syncthreads();
    for (int off = 1; off < 256; off <<= 1) {
        unsigned add = (t >= off) ? sh[t - off] : 0u;
        __syncthreads();
        sh[t] += add;
        __syncthreads();
    }
    unsigned excl = sh[t] - run;
#pragma unroll
    for (int j = 0; j < SCAN_R; j++)
        blockHist[(size_t)(SCAN_R * t + j) * K_BUCKETS + b] = excl + v[j];
    if (t == 255) bucketTotal[b] = sh[255];
}

__global__ __launch_bounds__(1024) void scan_buckets_kernel(const unsigned* __restrict__ bucketTotal,
                                                            unsigned* __restrict__ bucketStart) {
    __shared__ unsigned sh[1024];
    int t = threadIdx.x;
    unsigned v = (t < K_BUCKETS) ? bucketTotal[t] : 0u;
    sh[t] = v;
    __syncthreads();
    for (int off = 1; off < 1024; off <<= 1) {
        unsigned add = (t >= off) ? sh[t - off] : 0u;
        __syncthreads();
        sh[t] += add;
        __syncthreads();
    }
    if (t < K_BUCKETS) bucketStart[t] = sh[t] - v;
    if (t == K_BUCKETS - 1) bucketStart[K_BUCKETS] = sh[t];
}

// Entry packs: src (18b) | (dst & 2047) << 18   (29 bits, group-relative dst)
__global__ __launch_bounds__(256) void scatter_kernel(const int* __restrict__ src,
                                                      const int* __restrict__ dst,
                                                      const unsigned* __restrict__ blockHist,
                                                      const unsigned* __restrict__ bucketStart,
                                                      unsigned* __restrict__ sorted) {
    __shared__ unsigned s_hist[K_BUCKETS];
    __shared__ unsigned s_cur[K_BUCKETS];
    __shared__ int      s_base[K_BUCKETS];
    __shared__ unsigned ssum[256];
    __shared__ unsigned ent[CHUNK];
    __shared__ unsigned short bk[CHUNK];

    int t = threadIdx.x;
    int base = blockIdx.x * CHUNK;
    for (int i = t; i < K_BUCKETS; i += 256) s_hist[i] = 0;
    __syncthreads();

    for (int e = base + t; e < base + CHUNK; e += 256)
        atomicAdd(&s_hist[((unsigned)dst[e]) >> RANGE_SHIFT], 1u);
    __syncthreads();

    unsigned v[4], run = 0;
#pragma unroll
    for (int j = 0; j < 4; j++) {
        int idx = 4 * t + j;
        v[j] = (idx < K_BUCKETS) ? s_hist[idx] : 0u;
    }
#pragma unroll
    for (int j = 0; j < 4; j++) { unsigned tmp = v[j]; v[j] = run; run += tmp; }
    ssum[t] = run;
    __syncthreads();
    for (int off = 1; off < 256; off <<= 1) {
        unsigned add = (t >= off) ? ssum[t - off] : 0u;
        __syncthreads();
        ssum[t] += add;
        __syncthreads();
    }
    unsigned excl = ssum[t] - run;
    const unsigned* row = blockHist + (size_t)blockIdx.x * K_BUCKETS;
#pragma unroll
    for (int j = 0; j < 4; j++) {
        int idx = 4 * t + j;
        if (idx < K_BUCKETS) {
            unsigned st = excl + v[j];
            s_cur[idx] = st;
            s_base[idx] = (int)(bucketStart[idx] + row[idx]) - (int)st;
        }
    }
    __syncthreads();

    for (int e = base + t; e < base + CHUNK; e += 256) {
        unsigned d = (unsigned)dst[e];
        unsigned s = (unsigned)src[e];
        unsigned b = d >> RANGE_SHIFT;
        unsigned lpos = atomicAdd(&s_cur[b], 1u);
        ent[lpos] = s | ((d & 2047u) << 18);
        bk[lpos] = (unsigned short)b;
    }
    __syncthreads();

    for (int i = t; i < CHUNK; i += 256) {
        unsigned b = bk[i];
        sorted[s_base[b] + i] = ent[i];
    }
}

// ---------------- pass-2: in-place sub-sort by src-tile, deg fused ----------
// Grid: N_GROUPS*SUB. Block permutes its sub-chunk [c0,c1) by src-tile in LDS.
// Emits per-(sub-chunk,tile) run starts (u16) and per-sub-chunk node counts.
__global__ __launch_bounds__(256) void scatter2_kernel(unsigned* __restrict__ sorted,
                                                       const unsigned* __restrict__ bucketStart,
                                                       unsigned short* __restrict__ lstart,
                                                       unsigned short* __restrict__ pcnt) {
    __shared__ unsigned ent[CAP];
    __shared__ unsigned char bk[CAP];
    __shared__ unsigned cnt[G_NODES];
    __shared__ unsigned h[NT], cur[NT];
    int t = threadIdx.x;
    int g = blockIdx.x / SUB, s = blockIdx.x % SUB;
    int gS = bucketStart[8 * g];
    int gE = bucketStart[min(8 * g + 8, K_BUCKETS)];
    int len = gE - gS;
    int c0 = gS + (int)((long long)len * s / SUB);
    int c1 = gS + (int)((long long)len * (s + 1) / SUB);
    int n = c1 - c0;                                 // <= ~6030 << CAP
    for (int i = t; i < G_NODES; i += 256) cnt[i] = 0;
    if (t < NT) h[t] = 0;
    __syncthreads();
    for (int i = t; i < n; i += 256) {
        unsigned w = sorted[c0 + i];
        ent[i] = w;
        unsigned tl = (w & 0x3FFFFu) >> TSHIFT;
        bk[i] = (unsigned char)tl;
        atomicAdd(&h[tl], 1u);
        atomicAdd(&cnt[w >> 18], 1u);                // degree (group-local dst)
    }
    __syncthreads();
    if (t == 0) {
        unsigned r = 0;
        for (int j = 0; j < NT; j++) { unsigned c = h[j]; h[j] = r; cur[j] = r; r += c; }
    }
    __syncthreads();
    int lb = blockIdx.x * (NT + 1);
    if (t < NT) lstart[lb + t] = (unsigned short)h[t];
    if (t == 0) lstart[lb + NT] = (unsigned short)n;
    for (int i = t; i < n; i += 256) {
        unsigned r = atomicAdd(&cur[bk[i]], 1u);
        sorted[c0 + r] = ent[i];                     // block-exclusive range
    }
    for (int i = t; i < G_NODES; i += 256)
        pcnt[(size_t)blockIdx.x * G_NODES + i] = (unsigned short)cnt[i];
}

// ---------------- GCN phase ----------------

__global__ __launch_bounds__(256) void node1_kernel(const float2* __restrict__ x,
                                                    const unsigned short* __restrict__ pcnt,
                                                    float* __restrict__ dinv,
                                                    float2* __restrict__ u) {
    int i = blockIdx.x * 256 + threadIdx.x;
    if (i >= N_NODES) return;
    int g = i >> GSHIFT, l = i & (G_NODES - 1);
    unsigned c = 1;  // +1 self loop
#pragma unroll
    for (int s = 0; s < SUB; s++) c += pcnt[(size_t)(g * SUB + s) * G_NODES + l];
    float di = rsqrtf((float)c);
    dinv[i] = di;
    float2 xi = x[i];
    u[i] = make_float2(di * xi.x, di * xi.y);
}

// Block (g, p): accumulate tiles {p, p+P, ...} of group g into LDS acc[2048].
// Gathers from GLOBAL (L1-cached 16KB window per tile); sorted stream read
// nontemporally so it doesn't evict the window. Runs precomputed tile-major,
// distributed round-robin per wave.
__global__ __launch_bounds__(256) void agg_loc_kernel(const unsigned* __restrict__ sorted,
                                                      const unsigned* __restrict__ bucketStart,
                                                      const unsigned short* __restrict__ lstart,
                                                      const float2* __restrict__ table,
                                                      float2* __restrict__ part,
                                                      int P) {
    __shared__ float accX[G_NODES], accY[G_NODES];
    __shared__ int runS[MAXRUNS];
    __shared__ int runL[MAXRUNS];
    int t = threadIdx.x;
    int g = blockIdx.x / P, p = blockIdx.x % P;
    int gS = bucketStart[8 * g];
    int gE = bucketStart[min(8 * g + 8, K_BUCKETS)];
    int len = gE - gS;
    int ntp = (NT - p + P - 1) / P;                  // my tile count
    int runs = ntp * SUB;
    for (int i = t; i < G_NODES; i += 256) { accX[i] = 0.f; accY[i] = 0.f; }
    for (int i = t; i < runs; i += 256) {
        int tile = p + P * (i / SUB);
        int s = i % SUB;
        int c0 = gS + (int)((long long)len * s / SUB);
        int lb = (g * SUB + s) * (NT + 1);
        int st = lstart[lb + tile];
        int en = lstart[lb + tile + 1];
        runS[i] = c0 + st;
        runL[i] = en - st;
    }
    __syncthreads();
    int w = t >> 6, lane = t & 63;
    for (int r = w; r < runs; r += 4) {
        int st = runS[r], L = runL[r];
        for (int k = lane; k < L; k += 64) {
            unsigned e = __builtin_nontemporal_load(&sorted[st + k]);
            float2 v = table[e & 0x3FFFFu];
            unsigned l = e >> 18;
            atomicAdd(&accX[l], v.x);
            atomicAdd(&accY[l], v.y);
        }
    }
    __syncthreads();
    float2* po = part + (size_t)blockIdx.x * G_NODES;
    for (int i = t; i < G_NODES; i += 256) po[i] = make_float2(accX[i], accY[i]);
}

__global__ __launch_bounds__(256) void node2_kernel(const float2* __restrict__ u,
                                                    const float2* __restrict__ part,
                                                    const float* __restrict__ W1,
                                                    const float* __restrict__ b1,
                                                    const float* __restrict__ W2,
                                                    const float* __restrict__ dinv,
                                                    float2* __restrict__ g2,
                                                    int P) {
    int i = blockIdx.x * 256 + threadIdx.x;
    if (i >= N_NODES) return;
    int g = i >> GSHIFT, l = i & (G_NODES - 1);
    float ax = 0.f, ay = 0.f;
    for (int p = 0; p < P; p++) {
        float2 v = part[(size_t)(g * P + p) * G_NODES + l];
        ax += v.x; ay += v.y;
    }
    float di = dinv[i];
    float2 uu = u[i];
    float c0 = di * (ax + uu.x);
    float c1 = di * (ay + uu.y);
    float a0 = 0.f, a1 = 0.f;
#pragma unroll
    for (int f = 0; f < 16; f++) {
        float o = fmaxf(c0 * W1[f] + c1 * W1[16 + f] + b1[f], 0.f);  // W1 (2,16)
        a0 += o * W2[2 * f];                                         // W2 (16,2)
        a1 += o * W2[2 * f + 1];
    }
    g2[i] = make_float2(di * a0, di * a1);
}

__global__ __launch_bounds__(256) void node3_kernel(const float2* __restrict__ g2,
                                                    const float2* __restrict__ part,
                                                    const float* __restrict__ b2,
                                                    const float* __restrict__ dinv,
                                                    float2* __restrict__ out,
                                                    int P) {
    int i = blockIdx.x * 256 + threadIdx.x;
    if (i >= N_NODES) return;
    int g = i >> GSHIFT, l = i & (G_NODES - 1);
    float ax = 0.f, ay = 0.f;
    for (int p = 0; p < P; p++) {
        float2 v = part[(size_t)(g * P + p) * G_NODES + l];
        ax += v.x; ay += v.y;
    }
    float di = dinv[i];
    float2 gg = g2[i];
    out[i] = make_float2(di * (ax + gg.x) + b2[0],
                         di * (ay + gg.y) + b2[1]);
}

// ---------------- fallback path (R2-style, 8 MB ws) ----------------

__global__ __launch_bounds__(256) void fb_deg(const int* __restrict__ dst, int* __restrict__ degi) {
    int e = blockIdx.x * 256 + threadIdx.x;
    if (e < N_EDGES) atomicAdd(&degi[dst[e]], 1);
}
__global__ __launch_bounds__(256) void fb_node1(const float* __restrict__ x, const int* __restrict__ degi,
                                                float* __restrict__ dinv, float2* __restrict__ u) {
    int i = blockIdx.x * 256 + threadIdx.x;
    if (i >= N_NODES) return;
    float di = rsqrtf((float)(degi[i] + 1));
    dinv[i] = di;
    float2 xi = ((const float2*)x)[i];
    u[i] = make_float2(di * xi.x, di * xi.y);
}
__global__ __launch_bounds__(256) void fb_agg(const int* __restrict__ src, const int* __restrict__ dst,
                                              const float2* __restrict__ table, float* __restrict__ acc) {
    int e = blockIdx.x * 256 + threadIdx.x;
    if (e >= N_EDGES) return;
    float2 v = table[src[e]];
    size_t d = dst[e];
    unsafeAtomicAdd(&acc[2 * d], v.x);
    unsafeAtomicAdd(&acc[2 * d + 1], v.y);
}
__global__ __launch_bounds__(256) void fb_node2(const float2* __restrict__ u, const float2* __restrict__ A1,
                                                const float* __restrict__ W1, const float* __restrict__ b1,
                                                const float* __restrict__ W2, const float* __restrict__ dinv,
                                                float2* __restrict__ g2) {
    int i = blockIdx.x * 256 + threadIdx.x;
    if (i >= N_NODES) return;
    float di = dinv[i];
    float2 a = A1[i], uu = u[i];
    float c0 = di * (a.x + uu.x), c1 = di * (a.y + uu.y);
    float a0 = 0.f, a1 = 0.f;
#pragma unroll
    for (int f = 0; f < 16; f++) {
        float o = fmaxf(c0 * W1[f] + c1 * W1[16 + f] + b1[f], 0.f);
        a0 += o * W2[2 * f];
        a1 += o * W2[2 * f + 1];
    }
    g2[i] = make_float2(di * a0, di * a1);
}
__global__ __launch_bounds__(256) void fb_node3(const float2* __restrict__ g2, const float2* __restrict__ A2,
                                                const float* __restrict__ b2, const float* __restrict__ dinv,
                                                float2* __restrict__ out) {
    int i = blockIdx.x * 256 + threadIdx.x;
    if (i >= N_NODES) return;
    float di = dinv[i];
    float2 a = A2[i], g = g2[i];
    out[i] = make_float2(di * (a.x + g.x) + b2[0], di * (a.y + g.y) + b2[1]);
}

// ---------------- launcher ----------------

extern "C" void kernel_launch(void* const* d_in, const int* in_sizes, int n_in,
                              void* d_out, int out_size, void* d_ws, size_t ws_size,
                              hipStream_t stream) {
    const float* x  = (const float*)d_in[0];
    const float* W1 = (const float*)d_in[1];
    const float* b1 = (const float*)d_in[2];
    const float* W2 = (const float*)d_in[3];
    const float* b2 = (const float*)d_in[4];
    const int* ei   = (const int*)d_in[5];   // (2,E): row 0 = src, row 1 = dst
    const int* src = ei;
    const int* dst = ei + N_EDGES;
    float2* out = (float2*)d_out;

    // ws layout (4B words):
    //   sorted [12,800,000)
    //   region:
    //     lstart u16 [2156*99 = 213,444] -> 106,722 words, pad to 106,724
    //     overlay at region+106,724 (sequential in time):
    //       pcnt u16 [2156*2048] = 2,207,744 words   (scatter2 -> node1)
    //       part float2 [98*P*2048] = P*401,408 words (agg1 -> node3)
    //   bucketTotal [784]  bucketStart [784]
    //   dinv [200,000]  u [400,000]  g2 [400,000]
    //   blockHist (hist..scatter1) aliases region start: 2048*782 = 1,601,536
    //     words < any region size ✓ (dead before lstart/pcnt written)
    const size_t LPAD = 106724;
    const size_t FIXED = (size_t)N_EDGES + 784 + 784 + N_NODES + 4 * (size_t)N_NODES;
    auto need_for = [&](int P) {
        size_t region = LPAD + (size_t)2207744 > LPAD + (size_t)P * 401408
                        ? LPAD + 2207744 : LPAD + (size_t)P * 401408;
        return (FIXED + region) * 4;
    };
    int P = 0;
    if (ws_size >= need_for(7)) P = 7;
    else if (ws_size >= need_for(4)) P = 4;

    if (P > 0) {
        unsigned* sorted      = (unsigned*)d_ws;
        unsigned* region      = sorted + N_EDGES;
        unsigned* blockHist   = region;                       // phase A alias
        unsigned short* lstart = (unsigned short*)region;
        unsigned short* pcnt   = (unsigned short*)(region + LPAD);
        float2*   part        = (float2*)(region + LPAD);
        size_t REGION = LPAD + ((size_t)2207744 > (size_t)P * 401408
                                ? 2207744 : (size_t)P * 401408);
        unsigned* bucketTotal = region + REGION;
        unsigned* bucketStart = bucketTotal + 784;
        float*    dinv        = (float*)(bucketStart + 784);
        float2*   u           = (float2*)(dinv + N_NODES);
        float2*   g2          = u + N_NODES;

        constexpr int NB = (N_NODES + 255) / 256;
        hist_kernel<<<SORT_BLOCKS, 256, 0, stream>>>(dst, blockHist);
        scan_perblock_kernel<<<K_BUCKETS, 256, 0, stream>>>(blockHist, bucketTotal);
        scan_buckets_kernel<<<1, 1024, 0, stream>>>(bucketTotal, bucketStart);
        scatter_kernel<<<SORT_BLOCKS, 256, 0, stream>>>(src, dst, blockHist, bucketStart, sorted);
        scatter2_kernel<<<N_GROUPS * SUB, 256, 0, stream>>>(sorted, bucketStart, lstart, pcnt);
        node1_kernel<<<NB, 256, 0, stream>>>((const float2*)x, pcnt, dinv, u);
        agg_loc_kernel<<<N_GROUPS * P, 256, 0, stream>>>(sorted, bucketStart, lstart, u, part, P);
        node2_kernel<<<NB, 256, 0, stream>>>(u, part, W1, b1, W2, dinv, g2, P);
        agg_loc_kernel<<<N_GROUPS * P, 256, 0, stream>>>(sorted, bucketStart, lstart, g2, part, P);
        node3_kernel<<<NB, 256, 0, stream>>>(g2, part, b2, dinv, out, P);
    } else {
        // R2-style fallback (8 MB ws): global atomics, ~3.1 ms.
        float* ws = (float*)d_ws;
        int*   degi = (int*)ws;
        float* A1   = ws + N_NODES;
        float* A2   = A1 + 2 * (size_t)N_NODES;
        float* dinvF = A2 + 2 * (size_t)N_NODES;
        float2* uF  = (float2*)(dinvF + N_NODES);
        float2* g2F = uF + N_NODES;
        constexpr int EB = (N_EDGES + 255) / 256;
        constexpr int NB = (N_NODES + 255) / 256;
        hipMemsetAsync(degi, 0, 5 * (size_t)N_NODES * sizeof(float), stream);
        fb_deg<<<EB, 256, 0, stream>>>(dst, degi);
        fb_node1<<<NB, 256, 0, stream>>>(x, degi, dinvF, uF);
        fb_agg<<<EB, 256, 0, stream>>>(src, dst, uF, A1);
        fb_node2<<<NB, 256, 0, stream>>>(uF, (const float2*)A1, W1, b1, W2, dinvF, g2F);
        fb_agg<<<EB, 256, 0, stream>>>(src, dst, g2F, A2);
        fb_node3<<<NB, 256, 0, stream>>>(g2F, (const float2*)A2, b2, dinvF, out);
    }
}

// Round 9
// 588.365 us; speedup vs baseline: 1.7307x; 1.2568x over previous
//
#include <hip/hip_runtime.h>

// GCN 2-layer: N=200000, E=12800000, features 2 -> 16 -> 2.
// R2: rank trick -- aggregate only 2-dim vectors (before W1 / after W2).
// R4/R5: counting-sort by dst bucket (256 nodes) + LDS aggregation; scatter
//        as block-local LDS sort + coalesced copy-out.
// R6: bucket-split agg (SEG=4) -> 143us/pass.
// R7/R8 (tile-sorted gathers) FAILED: agg time = misses x latency / in-flight;
//        tiling cut misses but collapsed concurrency. Reverted.
// R9: attack the chain instead: 8-deep register pipeline in agg/deg
//     (8 coalesced entry loads -> 8 independent gathers in flight -> 16 LDS
//     atomics) halves dependent round-trips per edge and doubles outstanding
//     misses. deg gets SEG=8. Sort phase = R5-proven code, ws layout = R6's.

constexpr int N_NODES = 200000;
constexpr int N_EDGES = 12800000;
constexpr int RANGE_SHIFT = 8;                       // 256 nodes / bucket
constexpr int K_BUCKETS = (N_NODES + 255) / 256;     // 782
constexpr int SORT_BLOCKS = 2048;
constexpr int CHUNK = N_EDGES / SORT_BLOCKS;         // 6250 exactly
constexpr int SCAN_R = SORT_BLOCKS / 256;            // 8
constexpr int SEG = 4;                               // agg segments per bucket
constexpr int SEGD = 8;                              // deg segments per bucket

// ---------------- sort phase (R5-proven) ----------------

__global__ __launch_bounds__(256) void hist_kernel(const int* __restrict__ dst,
                                                   unsigned* __restrict__ blockHist) {
    __shared__ unsigned h[K_BUCKETS];
    for (int i = threadIdx.x; i < K_BUCKETS; i += 256) h[i] = 0;
    __syncthreads();
    int base = blockIdx.x * CHUNK;
    for (int e = base + threadIdx.x; e < base + CHUNK; e += 256)
        atomicAdd(&h[((unsigned)dst[e]) >> RANGE_SHIFT], 1u);
    __syncthreads();
    unsigned* row = blockHist + (size_t)blockIdx.x * K_BUCKETS;
    for (int i = threadIdx.x; i < K_BUCKETS; i += 256) row[i] = h[i];
}

__global__ __launch_bounds__(256) void scan_perblock_kernel(unsigned* __restrict__ blockHist,
                                                            unsigned* __restrict__ bucketTotal) {
    int b = blockIdx.x, t = threadIdx.x;
    unsigned v[SCAN_R], run = 0;
#pragma unroll
    for (int j = 0; j < SCAN_R; j++) v[j] = blockHist[(size_t)(SCAN_R * t + j) * K_BUCKETS + b];
#pragma unroll
    for (int j = 0; j < SCAN_R; j++) { unsigned tmp = v[j]; v[j] = run; run += tmp; }
    __shared__ unsigned sh[256];
    sh[t] = run;
    __syncthreads();
    for (int off = 1; off < 256; off <<= 1) {
        unsigned add = (t >= off) ? sh[t - off] : 0u;
        __syncthreads();
        sh[t] += add;
        __syncthreads();
    }
    unsigned excl = sh[t] - run;
#pragma unroll
    for (int j = 0; j < SCAN_R; j++)
        blockHist[(size_t)(SCAN_R * t + j) * K_BUCKETS + b] = excl + v[j];
    if (t == 255) bucketTotal[b] = sh[255];
}

__global__ __launch_bounds__(1024) void scan_buckets_kernel(const unsigned* __restrict__ bucketTotal,
                                                            unsigned* __restrict__ bucketStart) {
    __shared__ unsigned sh[1024];
    int t = threadIdx.x;
    unsigned v = (t < K_BUCKETS) ? bucketTotal[t] : 0u;
    sh[t] = v;
    __syncthreads();
    for (int off = 1; off < 1024; off <<= 1) {
        unsigned add = (t >= off) ? sh[t - off] : 0u;
        __syncthreads();
        sh[t] += add;
        __syncthreads();
    }
    if (t < K_BUCKETS) bucketStart[t] = sh[t] - v;
    if (t == K_BUCKETS - 1) bucketStart[K_BUCKETS] = sh[t];
}

// Packed 4B entry: src (18b) | local_dst (8b) << 18.
__global__ __launch_bounds__(256) void scatter_kernel(const int* __restrict__ src,
                                                      const int* __restrict__ dst,
                                                      const unsigned* __restrict__ blockHist,
                                                      const unsigned* __restrict__ bucketStart,
                                                      unsigned* __restrict__ sorted) {
    __shared__ unsigned s_hist[K_BUCKETS];
    __shared__ unsigned s_cur[K_BUCKETS];
    __shared__ int      s_base[K_BUCKETS];
    __shared__ unsigned ssum[256];
    __shared__ unsigned ent[CHUNK];
    __shared__ unsigned short bk[CHUNK];

    int t = threadIdx.x;
    int base = blockIdx.x * CHUNK;
    for (int i = t; i < K_BUCKETS; i += 256) s_hist[i] = 0;
    __syncthreads();

    for (int e = base + t; e < base + CHUNK; e += 256)
        atomicAdd(&s_hist[((unsigned)dst[e]) >> RANGE_SHIFT], 1u);
    __syncthreads();

    unsigned v[4], run = 0;
#pragma unroll
    for (int j = 0; j < 4; j++) {
        int idx = 4 * t + j;
        v[j] = (idx < K_BUCKETS) ? s_hist[idx] : 0u;
    }
#pragma unroll
    for (int j = 0; j < 4; j++) { unsigned tmp = v[j]; v[j] = run; run += tmp; }
    ssum[t] = run;
    __syncthreads();
    for (int off = 1; off < 256; off <<= 1) {
        unsigned add = (t >= off) ? ssum[t - off] : 0u;
        __syncthreads();
        ssum[t] += add;
        __syncthreads();
    }
    unsigned excl = ssum[t] - run;
    const unsigned* row = blockHist + (size_t)blockIdx.x * K_BUCKETS;
#pragma unroll
    for (int j = 0; j < 4; j++) {
        int idx = 4 * t + j;
        if (idx < K_BUCKETS) {
            unsigned st = excl + v[j];
            s_cur[idx] = st;
            s_base[idx] = (int)(bucketStart[idx] + row[idx]) - (int)st;
        }
    }
    __syncthreads();

    for (int e = base + t; e < base + CHUNK; e += 256) {
        unsigned d = (unsigned)dst[e];
        unsigned s = (unsigned)src[e];
        unsigned b = d >> RANGE_SHIFT;
        unsigned lpos = atomicAdd(&s_cur[b], 1u);
        ent[lpos] = s | ((d & 255u) << 18);
        bk[lpos] = (unsigned short)b;
    }
    __syncthreads();

    for (int i = t; i < CHUNK; i += 256) {
        unsigned b = bk[i];
        sorted[s_base[b] + i] = ent[i];
    }
}

// ---------------- GCN phase ----------------

// Degree partials: SEGD=8 segments per bucket, 8-deep entry pipeline.
__global__ __launch_bounds__(256) void deg_part_kernel(const unsigned* __restrict__ sorted,
                                                       const unsigned* __restrict__ bucketStart,
                                                       unsigned* __restrict__ pcnt) {
    __shared__ unsigned cnt[256];
    int t = threadIdx.x;
    cnt[t] = 0;
    __syncthreads();
    int b = blockIdx.x >> 3, s = blockIdx.x & 7;
    int s0 = bucketStart[b], len = bucketStart[b + 1] - s0;
    int e0 = s0 + (len * s) / SEGD;
    int e1 = s0 + (len * (s + 1)) / SEGD;
    int e = e0 + t;
    for (; e + 1792 < e1; e += 2048) {
        unsigned w0 = sorted[e],        w1 = sorted[e + 256];
        unsigned w2 = sorted[e + 512],  w3 = sorted[e + 768];
        unsigned w4 = sorted[e + 1024], w5 = sorted[e + 1280];
        unsigned w6 = sorted[e + 1536], w7 = sorted[e + 1792];
        atomicAdd(&cnt[(w0 >> 18) & 255u], 1u);
        atomicAdd(&cnt[(w1 >> 18) & 255u], 1u);
        atomicAdd(&cnt[(w2 >> 18) & 255u], 1u);
        atomicAdd(&cnt[(w3 >> 18) & 255u], 1u);
        atomicAdd(&cnt[(w4 >> 18) & 255u], 1u);
        atomicAdd(&cnt[(w5 >> 18) & 255u], 1u);
        atomicAdd(&cnt[(w6 >> 18) & 255u], 1u);
        atomicAdd(&cnt[(w7 >> 18) & 255u], 1u);
    }
    for (; e < e1; e += 256)
        atomicAdd(&cnt[(sorted[e] >> 18) & 255u], 1u);
    __syncthreads();
    pcnt[(size_t)blockIdx.x * 256 + t] = cnt[t];
}

__global__ __launch_bounds__(256) void node1_kernel(const float2* __restrict__ x,
                                                    const unsigned* __restrict__ pcnt,
                                                    float* __restrict__ dinv,
                                                    float2* __restrict__ u) {
    int i = blockIdx.x * 256 + threadIdx.x;
    if (i >= N_NODES) return;
    int b = i >> 8, l = i & 255;
    unsigned c = 1;  // +1 self loop
#pragma unroll
    for (int s = 0; s < SEGD; s++) c += pcnt[(size_t)(b * SEGD + s) * 256 + l];
    float di = rsqrtf((float)c);
    dinv[i] = di;
    float2 xi = x[i];
    u[i] = make_float2(di * xi.x, di * xi.y);
}

// Partial aggregation, 8-deep pipeline: 8 coalesced entry loads -> 8
// independent gathers in flight -> 16 LDS atomics. One dependent memory
// round-trip per 8 edges/lane (vs 2 RTs per 4 edges in R6).
__global__ __launch_bounds__(256) void agg_part_kernel(const unsigned* __restrict__ sorted,
                                                       const unsigned* __restrict__ bucketStart,
                                                       const float2* __restrict__ table,
                                                       float2* __restrict__ part) {
    __shared__ float ax[256], ay[256];
    int t = threadIdx.x;
    ax[t] = 0.f; ay[t] = 0.f;
    __syncthreads();
    int b = blockIdx.x >> 2, s = blockIdx.x & 3;
    int s0 = bucketStart[b], len = bucketStart[b + 1] - s0;
    int e0 = s0 + (len * s) / SEG;
    int e1 = s0 + (len * (s + 1)) / SEG;
    int e = e0 + t;
    for (; e + 1792 < e1; e += 2048) {
        unsigned w0 = sorted[e],        w1 = sorted[e + 256];
        unsigned w2 = sorted[e + 512],  w3 = sorted[e + 768];
        unsigned w4 = sorted[e + 1024], w5 = sorted[e + 1280];
        unsigned w6 = sorted[e + 1536], w7 = sorted[e + 1792];
        float2 v0 = table[w0 & 0x3FFFFu];
        float2 v1 = table[w1 & 0x3FFFFu];
        float2 v2 = table[w2 & 0x3FFFFu];
        float2 v3 = table[w3 & 0x3FFFFu];
        float2 v4 = table[w4 & 0x3FFFFu];
        float2 v5 = table[w5 & 0x3FFFFu];
        float2 v6 = table[w6 & 0x3FFFFu];
        float2 v7 = table[w7 & 0x3FFFFu];
        atomicAdd(&ax[(w0 >> 18) & 255u], v0.x); atomicAdd(&ay[(w0 >> 18) & 255u], v0.y);
        atomicAdd(&ax[(w1 >> 18) & 255u], v1.x); atomicAdd(&ay[(w1 >> 18) & 255u], v1.y);
        atomicAdd(&ax[(w2 >> 18) & 255u], v2.x); atomicAdd(&ay[(w2 >> 18) & 255u], v2.y);
        atomicAdd(&ax[(w3 >> 18) & 255u], v3.x); atomicAdd(&ay[(w3 >> 18) & 255u], v3.y);
        atomicAdd(&ax[(w4 >> 18) & 255u], v4.x); atomicAdd(&ay[(w4 >> 18) & 255u], v4.y);
        atomicAdd(&ax[(w5 >> 18) & 255u], v5.x); atomicAdd(&ay[(w5 >> 18) & 255u], v5.y);
        atomicAdd(&ax[(w6 >> 18) & 255u], v6.x); atomicAdd(&ay[(w6 >> 18) & 255u], v6.y);
        atomicAdd(&ax[(w7 >> 18) & 255u], v7.x); atomicAdd(&ay[(w7 >> 18) & 255u], v7.y);
    }
    for (; e < e1; e += 256) {
        unsigned w = sorted[e];
        float2 v = table[w & 0x3FFFFu];
        unsigned l = (w >> 18) & 255u;
        atomicAdd(&ax[l], v.x);
        atomicAdd(&ay[l], v.y);
    }
    __syncthreads();
    part[(size_t)blockIdx.x * 256 + t] = make_float2(ax[t], ay[t]);
}

__global__ __launch_bounds__(256) void node2_kernel(const float2* __restrict__ u,
                                                    const float2* __restrict__ part,
                                                    const float* __restrict__ W1,
                                                    const float* __restrict__ b1,
                                                    const float* __restrict__ W2,
                                                    const float* __restrict__ dinv,
                                                    float2* __restrict__ g2) {
    int i = blockIdx.x * 256 + threadIdx.x;
    if (i >= N_NODES) return;
    int b = i >> 8, l = i & 255;
    float ax = 0.f, ay = 0.f;
#pragma unroll
    for (int s = 0; s < SEG; s++) {
        float2 p = part[(size_t)(b * SEG + s) * 256 + l];
        ax += p.x; ay += p.y;
    }
    float di = dinv[i];
    float2 uu = u[i];
    float c0 = di * (ax + uu.x);
    float c1 = di * (ay + uu.y);
    float a0 = 0.f, a1 = 0.f;
#pragma unroll
    for (int f = 0; f < 16; f++) {
        float o = fmaxf(c0 * W1[f] + c1 * W1[16 + f] + b1[f], 0.f);  // W1 (2,16)
        a0 += o * W2[2 * f];                                         // W2 (16,2)
        a1 += o * W2[2 * f + 1];
    }
    g2[i] = make_float2(di * a0, di * a1);
}

__global__ __launch_bounds__(256) void node3_kernel(const float2* __restrict__ g2,
                                                    const float2* __restrict__ part,
                                                    const float* __restrict__ b2,
                                                    const float* __restrict__ dinv,
                                                    float2* __restrict__ out) {
    int i = blockIdx.x * 256 + threadIdx.x;
    if (i >= N_NODES) return;
    int b = i >> 8, l = i & 255;
    float ax = 0.f, ay = 0.f;
#pragma unroll
    for (int s = 0; s < SEG; s++) {
        float2 p = part[(size_t)(b * SEG + s) * 256 + l];
        ax += p.x; ay += p.y;
    }
    float di = dinv[i];
    float2 g = g2[i];
    out[i] = make_float2(di * (ax + g.x) + b2[0],
                         di * (ay + g.y) + b2[1]);
}

// ---------------- fallback path (R2-style, needs only 8 MB ws) ----------------

__global__ __launch_bounds__(256) void fb_deg(const int* __restrict__ dst, int* __restrict__ degi) {
    int e = blockIdx.x * 256 + threadIdx.x;
    if (e < N_EDGES) atomicAdd(&degi[dst[e]], 1);
}
__global__ __launch_bounds__(256) void fb_node1(const float* __restrict__ x, const int* __restrict__ degi,
                                                float* __restrict__ dinv, float2* __restrict__ u) {
    int i = blockIdx.x * 256 + threadIdx.x;
    if (i >= N_NODES) return;
    float di = rsqrtf((float)(degi[i] + 1));
    dinv[i] = di;
    float2 xi = ((const float2*)x)[i];
    u[i] = make_float2(di * xi.x, di * xi.y);
}
__global__ __launch_bounds__(256) void fb_agg(const int* __restrict__ src, const int* __restrict__ dst,
                                              const float2* __restrict__ table, float* __restrict__ acc) {
    int e = blockIdx.x * 256 + threadIdx.x;
    if (e >= N_EDGES) return;
    float2 v = table[src[e]];
    size_t d = dst[e];
    unsafeAtomicAdd(&acc[2 * d], v.x);
    unsafeAtomicAdd(&acc[2 * d + 1], v.y);
}
__global__ __launch_bounds__(256) void fb_node2(const float2* __restrict__ u, const float2* __restrict__ A1,
                                                const float* __restrict__ W1, const float* __restrict__ b1,
                                                const float* __restrict__ W2, const float* __restrict__ dinv,
                                                float2* __restrict__ g2) {
    int i = blockIdx.x * 256 + threadIdx.x;
    if (i >= N_NODES) return;
    float di = dinv[i];
    float2 a = A1[i], uu = u[i];
    float c0 = di * (a.x + uu.x), c1 = di * (a.y + uu.y);
    float a0 = 0.f, a1 = 0.f;
#pragma unroll
    for (int f = 0; f < 16; f++) {
        float o = fmaxf(c0 * W1[f] + c1 * W1[16 + f] + b1[f], 0.f);
        a0 += o * W2[2 * f];
        a1 += o * W2[2 * f + 1];
    }
    g2[i] = make_float2(di * a0, di * a1);
}
__global__ __launch_bounds__(256) void fb_node3(const float2* __restrict__ g2, const float2* __restrict__ A2,
                                                const float* __restrict__ b2, const float* __restrict__ dinv,
                                                float2* __restrict__ out) {
    int i = blockIdx.x * 256 + threadIdx.x;
    if (i >= N_NODES) return;
    float di = dinv[i];
    float2 a = A2[i], g = g2[i];
    out[i] = make_float2(di * (a.x + g.x) + b2[0], di * (a.y + g.y) + b2[1]);
}

// ---------------- launcher ----------------

extern "C" void kernel_launch(void* const* d_in, const int* in_sizes, int n_in,
                              void* d_out, int out_size, void* d_ws, size_t ws_size,
                              hipStream_t stream) {
    const float* x  = (const float*)d_in[0];
    const float* W1 = (const float*)d_in[1];
    const float* b1 = (const float*)d_in[2];
    const float* W2 = (const float*)d_in[3];
    const float* b2 = (const float*)d_in[4];
    const int* ei   = (const int*)d_in[5];   // (2,E): row 0 = src, row 1 = dst
    const int* src = ei;
    const int* dst = ei + N_EDGES;
    float2* out = (float2*)d_out;

    // ws layout (4B words), R6's proven ~61.6 MB total:
    //   sorted      [E]                      12,800,000
    //   region      [SORT_BLOCKS*K]           1,601,536  -- time-multiplexed:
    //       blockHist u32 (hist..scatter)     1,601,536 words
    //       pcnt u32 [6256*256]               1,601,536 words (deg..node1)
    //       part float2 [3128*256]            1,601,536 words (agg1..node3)
    //   bucketTotal [K]  782 (+2 pad)
    //   bucketStart [K+1] 784
    //   dinv [N]  u [2N]  g2 [2N]
    const size_t need = ((size_t)N_EDGES + (size_t)SORT_BLOCKS * K_BUCKETS + 784 + 784
                         + N_NODES + 2 * (size_t)N_NODES + 2 * (size_t)N_NODES) * 4;

    if (ws_size >= need) {
        unsigned* sorted      = (unsigned*)d_ws;
        unsigned* region      = sorted + N_EDGES;
        unsigned* blockHist   = region;
        unsigned* pcnt        = region;            // deg partials (reuse)
        float2*   part        = (float2*)region;   // agg partials (reuse)
        unsigned* bucketTotal = region + (size_t)SORT_BLOCKS * K_BUCKETS;
        unsigned* bucketStart = bucketTotal + 784;
        float*    dinv        = (float*)(bucketStart + 784);
        float2*   u           = (float2*)(dinv + N_NODES);
        float2*   g2          = u + N_NODES;

        constexpr int NB = (N_NODES + 255) / 256;
        hist_kernel<<<SORT_BLOCKS, 256, 0, stream>>>(dst, blockHist);
        scan_perblock_kernel<<<K_BUCKETS, 256, 0, stream>>>(blockHist, bucketTotal);
        scan_buckets_kernel<<<1, 1024, 0, stream>>>(bucketTotal, bucketStart);
        scatter_kernel<<<SORT_BLOCKS, 256, 0, stream>>>(src, dst, blockHist, bucketStart, sorted);
        deg_part_kernel<<<K_BUCKETS * SEGD, 256, 0, stream>>>(sorted, bucketStart, pcnt);
        node1_kernel<<<NB, 256, 0, stream>>>((const float2*)x, pcnt, dinv, u);
        agg_part_kernel<<<K_BUCKETS * SEG, 256, 0, stream>>>(sorted, bucketStart, u, part);
        node2_kernel<<<NB, 256, 0, stream>>>(u, part, W1, b1, W2, dinv, g2);
        agg_part_kernel<<<K_BUCKETS * SEG, 256, 0, stream>>>(sorted, bucketStart, g2, part);
        node3_kernel<<<NB, 256, 0, stream>>>(g2, part, b2, dinv, out);
    } else {
        // R2-style fallback (8 MB ws): global atomics, ~3.1 ms.
        float* ws = (float*)d_ws;
        int*   degi = (int*)ws;
        float* A1   = ws + N_NODES;
        float* A2   = A1 + 2 * (size_t)N_NODES;
        float* dinvF = A2 + 2 * (size_t)N_NODES;
        float2* uF  = (float2*)(dinvF + N_NODES);
        float2* g2F = uF + N_NODES;
        constexpr int EB = (N_EDGES + 255) / 256;
        constexpr int NB = (N_NODES + 255) / 256;
        hipMemsetAsync(degi, 0, 5 * (size_t)N_NODES * sizeof(float), stream);
        fb_deg<<<EB, 256, 0, stream>>>(dst, degi);
        fb_node1<<<NB, 256, 0, stream>>>(x, degi, dinvF, uF);
        fb_agg<<<EB, 256, 0, stream>>>(src, dst, uF, A1);
        fb_node2<<<NB, 256, 0, stream>>>(uF, (const float2*)A1, W1, b1, W2, dinvF, g2F);
        fb_agg<<<EB, 256, 0, stream>>>(src, dst, g2F, A2);
        fb_node3<<<NB, 256, 0, stream>>>(g2F, (const float2*)A2, b2, dinvF, out);
    }
}